// Round 1
// baseline (5348.482 us; speedup 1.0000x reference)
//
#include <hip/hip_runtime.h>
#include <cstdint>

#define NSTEPS 100

// 100 per-step threefry subkeys, passed by value through kernargs (800 B < 4 KB).
struct KeyArr {
    uint32_t k1[NSTEPS];
    uint32_t k2[NSTEPS];
};

__host__ __device__ __forceinline__ uint32_t rotl32(uint32_t x, uint32_t r) {
    return (x << r) | (x >> (32u - r));
}

// One threefry2x32 block, JAX/XLA round schedule (20 rounds, 5 key injections).
// Input words (x0, x1) are the counter pair; (k1, k2) the key pair.
__host__ __device__ __forceinline__ void threefry2x32(
    uint32_t k1, uint32_t k2, uint32_t x0, uint32_t x1,
    uint32_t& o0, uint32_t& o1) {
    const uint32_t ks2 = k1 ^ k2 ^ 0x1BD11BDAu;
    x0 += k1; x1 += k2;
#define TF_R(r) { x0 += x1; x1 = rotl32(x1, r); x1 ^= x0; }
    TF_R(13u) TF_R(15u) TF_R(26u) TF_R(6u)   x0 += k2;  x1 += ks2 + 1u;
    TF_R(17u) TF_R(29u) TF_R(16u) TF_R(24u)  x0 += ks2; x1 += k1 + 2u;
    TF_R(13u) TF_R(15u) TF_R(26u) TF_R(6u)   x0 += k1;  x1 += k2 + 3u;
    TF_R(17u) TF_R(29u) TF_R(16u) TF_R(24u)  x0 += k2;  x1 += ks2 + 4u;
    TF_R(13u) TF_R(15u) TF_R(26u) TF_R(6u)   x0 += ks2; x1 += k1 + 5u;
#undef TF_R
    o0 = x0; o1 = x1;
}

// bits -> standard normal, replicating JAX: uniform in [nextafter(-1,0), 1),
// then sqrt(2) * erfinv(u) with XLA's f32 ErfInv (Giles) polynomials.
__device__ __forceinline__ float bits_to_normal(uint32_t bits) {
    const float MINVAL = -0.99999994f;  // nextafter(-1, 0) in f32
    float f = __uint_as_float((bits >> 9) | 0x3f800000u) - 1.0f;  // [0, 1)
    float u = f * 2.0f + MINVAL;       // (maxval - minval) rounds to exactly 2.0f
    u = fmaxf(u, MINVAL);
    float w = -log1pf(-u * u);
    float p;
    if (w < 5.0f) {
        w = w - 2.5f;
        p =              2.81022636e-08f;
        p = fmaf(p, w,   3.43273939e-07f);
        p = fmaf(p, w,  -3.5233877e-06f);
        p = fmaf(p, w,  -4.39150654e-06f);
        p = fmaf(p, w,   0.00021858087f);
        p = fmaf(p, w,  -0.00125372503f);
        p = fmaf(p, w,  -0.00417768164f);
        p = fmaf(p, w,   0.246640727f);
        p = fmaf(p, w,   1.50140941f);
    } else {
        w = sqrtf(w) - 3.0f;
        p =             -0.000200214257f;
        p = fmaf(p, w,   0.000100950558f);
        p = fmaf(p, w,   0.00134934322f);
        p = fmaf(p, w,  -0.00367342844f);
        p = fmaf(p, w,   0.00573950773f);
        p = fmaf(p, w,  -0.0076224613f);
        p = fmaf(p, w,   0.00943887047f);
        p = fmaf(p, w,   1.00167406f);
        p = fmaf(p, w,   2.83297682f);
    }
    return 1.41421356f * (p * u);  // sqrt(2) in f32
}

__global__ __launch_bounds__(256)
void DiffusionProcess_21698174780217_kernel(
    const float* __restrict__ x, const float* __restrict__ betas,
    float* __restrict__ out, KeyArr keys, int n4) {
    __shared__ float sb[NSTEPS];
    const int t = threadIdx.x;
    if (t < NSTEPS) sb[t] = sqrtf(betas[t]);
    __syncthreads();

    const int gid = blockIdx.x * blockDim.x + t;
    if (gid >= n4) return;
    const uint32_t base = (uint32_t)gid * 4u;

    float acc0 = 0.f, acc1 = 0.f, acc2 = 0.f, acc3 = 0.f;

    #pragma unroll 1
    for (int s = 0; s < NSTEPS; ++s) {
        const uint32_t k1 = keys.k1[s];
        const uint32_t k2 = keys.k2[s];
        const float sbs = sb[s];
        uint32_t a0, a1, b0, b1, c0, c1, d0, d1;
        // 4 independent ciphers (counter hi word = 0: n < 2^32) for ILP.
        threefry2x32(k1, k2, 0u, base + 0u, a0, a1);
        threefry2x32(k1, k2, 0u, base + 1u, b0, b1);
        threefry2x32(k1, k2, 0u, base + 2u, c0, c1);
        threefry2x32(k1, k2, 0u, base + 3u, d0, d1);
        acc0 = fmaf(sbs, bits_to_normal(a0 ^ a1), acc0);
        acc1 = fmaf(sbs, bits_to_normal(b0 ^ b1), acc1);
        acc2 = fmaf(sbs, bits_to_normal(c0 ^ c1), acc2);
        acc3 = fmaf(sbs, bits_to_normal(d0 ^ d1), acc3);
    }

    const float4 xv = reinterpret_cast<const float4*>(x)[gid];
    float4 ov;
    ov.x = xv.x + acc0;
    ov.y = xv.y + acc1;
    ov.z = xv.z + acc2;
    ov.w = xv.w + acc3;
    reinterpret_cast<float4*>(out)[gid] = ov;
}

extern "C" void kernel_launch(void* const* d_in, const int* in_sizes, int n_in,
                              void* d_out, int out_size, void* d_ws, size_t ws_size,
                              hipStream_t stream) {
    const float* x = (const float*)d_in[0];
    const float* betas = (const float*)d_in[1];
    float* out = (float*)d_out;
    const int n = in_sizes[0];       // 64*3*256*256 = 12,582,912 (divisible by 4)
    const int n4 = n / 4;

    // jax.random.key(1) -> key data (0, 1).
    // split (partitionable / foldlike): keys[s] = threefry2x32((0,1), (0, s)).
    KeyArr keys;
    for (int s = 0; s < NSTEPS; ++s) {
        uint32_t o0, o1;
        threefry2x32(0u, 1u, 0u, (uint32_t)s, o0, o1);
        keys.k1[s] = o0;
        keys.k2[s] = o1;
    }

    const int blocks = (n4 + 255) / 256;
    hipLaunchKernelGGL(DiffusionProcess_21698174780217_kernel,
                       dim3(blocks), dim3(256), 0, stream,
                       x, betas, out, keys, n4);
}

// Round 2
// 2303.793 us; speedup vs baseline: 2.3216x; 2.3216x over previous
//
#include <hip/hip_runtime.h>
#include <cstdint>

#define NSTEPS 100

// 100 per-step threefry subkeys, passed by value through kernargs (800 B < 4 KB).
struct KeyArr {
    uint32_t k1[NSTEPS];
    uint32_t k2[NSTEPS];
};

__host__ __device__ __forceinline__ uint32_t rotl32(uint32_t x, uint32_t r) {
    return (x << r) | (x >> (32u - r));   // -> v_alignbit_b32, 1 instr
}

// One threefry2x32 block, JAX/XLA round schedule (20 rounds, 5 key injections).
__host__ __device__ __forceinline__ void threefry2x32(
    uint32_t k1, uint32_t k2, uint32_t x0, uint32_t x1,
    uint32_t& o0, uint32_t& o1) {
    const uint32_t ks2 = k1 ^ k2 ^ 0x1BD11BDAu;
    x0 += k1; x1 += k2;
#define TF_R(r) { x0 += x1; x1 = rotl32(x1, r); x1 ^= x0; }
    TF_R(13u) TF_R(15u) TF_R(26u) TF_R(6u)   x0 += k2;  x1 += ks2 + 1u;
    TF_R(17u) TF_R(29u) TF_R(16u) TF_R(24u)  x0 += ks2; x1 += k1 + 2u;
    TF_R(13u) TF_R(15u) TF_R(26u) TF_R(6u)   x0 += k1;  x1 += k2 + 3u;
    TF_R(17u) TF_R(29u) TF_R(16u) TF_R(24u)  x0 += k2;  x1 += ks2 + 4u;
    TF_R(13u) TF_R(15u) TF_R(26u) TF_R(6u)   x0 += ks2; x1 += k1 + 5u;
#undef TF_R
    o0 = x0; o1 = x1;
}

// bits -> erfinv(u)-shaped value p*u (caller folds the sqrt(2) factor into the
// per-step scale). Replicates JAX/XLA semantics:
//   u in [nextafter(-1,0), 1), n = sqrt(2)*erfinv(u), XLA Giles polynomials.
// Differences vs R0 (all inside the ~10x error margin):
//  - fmaxf dropped: u = fma(f,2,MINVAL) with f>=0 can't round below MINVAL.
//  - w = -log1p(-u*u) computed as -ln2*v_log_f32((1-|u|)*(1+|u|)).
//    Sterbenz: 1-|u| exact for |u|>=0.5, so no cancellation blowup in the tail.
//  - raw v_sqrt_f32 in the rare (0.33% of lanes) far branch.
__device__ __forceinline__ float bits_to_scaled_normal(uint32_t bits) {
    const float MINVAL = -0.99999994f;  // nextafter(-1, 0) in f32
    float f = __uint_as_float((bits >> 9) | 0x3f800000u) - 1.0f;  // [0, 1)
    float u = fmaf(f, 2.0f, MINVAL);    // [MINVAL, 0.99999994]
    float au = fabsf(u);                // folds into src modifiers
    float t = (1.0f - au) * (1.0f + au);          // == 1-u^2, high rel acc
    float w = __builtin_amdgcn_logf(t) * (-0.69314718056f);  // -ln(1-u^2)
    float p;
    if (w < 5.0f) {
        w = w - 2.5f;
        p =              2.81022636e-08f;
        p = fmaf(p, w,   3.43273939e-07f);
        p = fmaf(p, w,  -3.5233877e-06f);
        p = fmaf(p, w,  -4.39150654e-06f);
        p = fmaf(p, w,   0.00021858087f);
        p = fmaf(p, w,  -0.00125372503f);
        p = fmaf(p, w,  -0.00417768164f);
        p = fmaf(p, w,   0.246640727f);
        p = fmaf(p, w,   1.50140941f);
    } else {
        w = __builtin_amdgcn_sqrtf(w) - 3.0f;
        p =             -0.000200214257f;
        p = fmaf(p, w,   0.000100950558f);
        p = fmaf(p, w,   0.00134934322f);
        p = fmaf(p, w,  -0.00367342844f);
        p = fmaf(p, w,   0.00573950773f);
        p = fmaf(p, w,  -0.0076224613f);
        p = fmaf(p, w,   0.00943887047f);
        p = fmaf(p, w,   1.00167406f);
        p = fmaf(p, w,   2.83297682f);
    }
    return p * u;   // scaled normal = sqrt(2*beta) * (p*u), done by caller
}

__global__ __launch_bounds__(256)
void DiffusionProcess_21698174780217_kernel(
    const float* __restrict__ x, const float* __restrict__ betas,
    float* __restrict__ out, KeyArr keys, int n4) {
    __shared__ float sb[NSTEPS];
    const int t = threadIdx.x;
    if (t < NSTEPS) sb[t] = __builtin_amdgcn_sqrtf(betas[t] * 2.0f); // sqrt(2*beta)
    __syncthreads();

    const int gid = blockIdx.x * blockDim.x + t;
    if (gid >= n4) return;
    const uint32_t base = (uint32_t)gid * 4u;

    float acc0 = 0.f, acc1 = 0.f, acc2 = 0.f, acc3 = 0.f;

    #pragma unroll 1
    for (int s = 0; s < NSTEPS; ++s) {
        const uint32_t k1 = keys.k1[s];
        const uint32_t k2 = keys.k2[s];
        const float sbs = sb[s];
        uint32_t a0, a1, b0, b1, c0, c1, d0, d1;
        // 4 independent ciphers (counter hi word = 0: n < 2^32).
        threefry2x32(k1, k2, 0u, base + 0u, a0, a1);
        threefry2x32(k1, k2, 0u, base + 1u, b0, b1);
        threefry2x32(k1, k2, 0u, base + 2u, c0, c1);
        threefry2x32(k1, k2, 0u, base + 3u, d0, d1);
        acc0 = fmaf(sbs, bits_to_scaled_normal(a0 ^ a1), acc0);
        acc1 = fmaf(sbs, bits_to_scaled_normal(b0 ^ b1), acc1);
        acc2 = fmaf(sbs, bits_to_scaled_normal(c0 ^ c1), acc2);
        acc3 = fmaf(sbs, bits_to_scaled_normal(d0 ^ d1), acc3);
    }

    const float4 xv = reinterpret_cast<const float4*>(x)[gid];
    float4 ov;
    ov.x = xv.x + acc0;
    ov.y = xv.y + acc1;
    ov.z = xv.z + acc2;
    ov.w = xv.w + acc3;
    reinterpret_cast<float4*>(out)[gid] = ov;
}

extern "C" void kernel_launch(void* const* d_in, const int* in_sizes, int n_in,
                              void* d_out, int out_size, void* d_ws, size_t ws_size,
                              hipStream_t stream) {
    const float* x = (const float*)d_in[0];
    const float* betas = (const float*)d_in[1];
    float* out = (float*)d_out;
    const int n = in_sizes[0];       // 64*3*256*256 = 12,582,912 (divisible by 4)
    const int n4 = n / 4;

    // jax.random.key(1) -> key data (0, 1).
    // split (partitionable / foldlike): keys[s] = threefry2x32((0,1), (0, s)).
    KeyArr keys;
    for (int s = 0; s < NSTEPS; ++s) {
        uint32_t o0, o1;
        threefry2x32(0u, 1u, 0u, (uint32_t)s, o0, o1);
        keys.k1[s] = o0;
        keys.k2[s] = o1;
    }

    const int blocks = (n4 + 255) / 256;
    hipLaunchKernelGGL(DiffusionProcess_21698174780217_kernel,
                       dim3(blocks), dim3(256), 0, stream,
                       x, betas, out, keys, n4);
}

// Round 3
// 2241.925 us; speedup vs baseline: 2.3857x; 1.0276x over previous
//
#include <hip/hip_runtime.h>
#include <cstdint>

#define NSTEPS 100

// 100 per-step threefry subkeys, passed by value through kernargs (800 B < 4 KB).
struct KeyArr {
    uint32_t k1[NSTEPS];
    uint32_t k2[NSTEPS];
};

__host__ __device__ __forceinline__ uint32_t rotl32(uint32_t x, uint32_t r) {
    return (x << r) | (x >> (32u - r));   // -> v_alignbit_b32, 1 instr
}

// Host-side reference threefry (key derivation only).
static void threefry2x32_host(uint32_t k1, uint32_t k2, uint32_t x0, uint32_t x1,
                              uint32_t& o0, uint32_t& o1) {
    const uint32_t ks2 = k1 ^ k2 ^ 0x1BD11BDAu;
    x0 += k1; x1 += k2;
#define TF_R(r) { x0 += x1; x1 = rotl32(x1, r); x1 ^= x0; }
    TF_R(13u) TF_R(15u) TF_R(26u) TF_R(6u)   x0 += k2;  x1 += ks2 + 1u;
    TF_R(17u) TF_R(29u) TF_R(16u) TF_R(24u)  x0 += ks2; x1 += k1 + 2u;
    TF_R(13u) TF_R(15u) TF_R(26u) TF_R(6u)   x0 += k1;  x1 += k2 + 3u;
    TF_R(17u) TF_R(29u) TF_R(16u) TF_R(24u)  x0 += k2;  x1 += ks2 + 4u;
    TF_R(13u) TF_R(15u) TF_R(26u) TF_R(6u)   x0 += ks2; x1 += k1 + 5u;
#undef TF_R
    o0 = x0; o1 = x1;
}

// Device cipher, op-trimmed but bit-identical to the above:
//  - x0 init is uniform k1 (SGPR); round 1 is a single v_add with SGPR src.
//  - each mid-schedule key injection is fused into the next round's add:
//      x1 += kb;  x0 = x0 + ka + x1;   // -> v_add3_u32 (1 SGPR operand)
//  - key-only constants (ks2+c, k1+c, ...) are uniform -> scalar pipe, free.
// 67 VALU ops + 1 output xor.
__device__ __forceinline__ uint32_t tf_bits(uint32_t k1, uint32_t k2, uint32_t ctr_pk2) {
    const uint32_t ks2 = k1 ^ k2 ^ 0x1BD11BDAu;
    uint32_t x1 = ctr_pk2;              // = counter + k2, computed by caller
    uint32_t x0 = k1 + x1;              // init(x0=k1) fused with round-1 add
    x1 = rotl32(x1, 13u); x1 ^= x0;
#define TF_R(r)            { x0 += x1; x1 = rotl32(x1, r); x1 ^= x0; }
#define TF_RINJ(r, ka, kb) { x1 += (kb); x0 = x0 + (ka) + x1; x1 = rotl32(x1, r); x1 ^= x0; }
    TF_R(15u) TF_R(26u) TF_R(6u)
    TF_RINJ(17u, k2,  ks2 + 1u)
    TF_R(29u) TF_R(16u) TF_R(24u)
    TF_RINJ(13u, ks2, k1 + 2u)
    TF_R(15u) TF_R(26u) TF_R(6u)
    TF_RINJ(17u, k1,  k2 + 3u)
    TF_R(29u) TF_R(16u) TF_R(24u)
    TF_RINJ(13u, k2,  ks2 + 4u)
    TF_R(15u) TF_R(26u) TF_R(6u)
    x0 += ks2; x1 += k1 + 5u;
#undef TF_R
#undef TF_RINJ
    return x0 ^ x1;
}

// bits -> erfinv-shaped p*u (caller folds sqrt(2*beta) into one fmac).
// JAX/XLA semantics: u in [nextafter(-1,0), 1), XLA Giles polynomials.
// Op-trimmed vs R1:
//  - (bits>>9)|0x3f800000 as one v_alignbit: funnel(127:bits)>>9.
//  - t = 1-u^2 via single fma (more accurate than the 3-op Sterbenz product:
//    exact multiply + one rounding, full relative precision as t->0).
//  - branch compares raw v_log output against -5/ln2; central path folds
//    *(-ln2) and -2.5 into one fma.
__device__ __forceinline__ float bits_to_scaled_normal(uint32_t bits) {
    const float MINVAL = -0.99999994f;  // nextafter(-1, 0) in f32
    float b = __uint_as_float(__builtin_amdgcn_alignbit(127u, bits, 9u)); // [1,2)
    float f = b - 1.0f;                 // exact (Sterbenz)
    float u = fmaf(f, 2.0f, MINVAL);    // [MINVAL, 0.99999994]
    float au = fabsf(u);                // src modifier, free on consumer
    float t = fmaf(-au, au, 1.0f);      // 1 - u^2, single rounding
    float lg = __builtin_amdgcn_logf(t);        // log2(1-u^2), quarter-rate
    float p;
    if (lg > -7.2134752f) {             // w = -ln2*lg < 5  (central, 99.67%)
        float w = fmaf(lg, -0.69314718056f, -2.5f);
        p =              2.81022636e-08f;
        p = fmaf(p, w,   3.43273939e-07f);
        p = fmaf(p, w,  -3.5233877e-06f);
        p = fmaf(p, w,  -4.39150654e-06f);
        p = fmaf(p, w,   0.00021858087f);
        p = fmaf(p, w,  -0.00125372503f);
        p = fmaf(p, w,  -0.00417768164f);
        p = fmaf(p, w,   0.246640727f);
        p = fmaf(p, w,   1.50140941f);
    } else {                            // rare tail: ~0.33% of lanes
        float w0 = lg * -0.69314718056f;
        float w = __builtin_amdgcn_sqrtf(w0) - 3.0f;
        p =             -0.000200214257f;
        p = fmaf(p, w,   0.000100950558f);
        p = fmaf(p, w,   0.00134934322f);
        p = fmaf(p, w,  -0.00367342844f);
        p = fmaf(p, w,   0.00573950773f);
        p = fmaf(p, w,  -0.0076224613f);
        p = fmaf(p, w,   0.00943887047f);
        p = fmaf(p, w,   1.00167406f);
        p = fmaf(p, w,   2.83297682f);
    }
    return p * u;
}

__global__ __launch_bounds__(256)
void DiffusionProcess_21698174780217_kernel(
    const float* __restrict__ x, const float* __restrict__ betas,
    float* __restrict__ out, KeyArr keys, int n4) {
    __shared__ float sb[NSTEPS];
    const int t = threadIdx.x;
    if (t < NSTEPS) sb[t] = __builtin_amdgcn_sqrtf(betas[t] * 2.0f); // sqrt(2*beta)
    __syncthreads();

    const int gid = blockIdx.x * blockDim.x + t;
    if (gid >= n4) return;
    const uint32_t base = (uint32_t)gid * 4u;

    float acc0 = 0.f, acc1 = 0.f, acc2 = 0.f, acc3 = 0.f;

    #pragma unroll 1
    for (int s = 0; s < NSTEPS; ++s) {
        const uint32_t k1 = keys.k1[s];
        const uint32_t k2 = keys.k2[s];
        const float sbs = sb[s];
        // counter hi word = 0 (n < 2^32); x1 init = counter + k2 (1 VALU each)
        uint32_t r0 = tf_bits(k1, k2, (base + 0u) + k2);
        uint32_t r1 = tf_bits(k1, k2, (base + 1u) + k2);
        uint32_t r2 = tf_bits(k1, k2, (base + 2u) + k2);
        uint32_t r3 = tf_bits(k1, k2, (base + 3u) + k2);
        acc0 = fmaf(sbs, bits_to_scaled_normal(r0), acc0);
        acc1 = fmaf(sbs, bits_to_scaled_normal(r1), acc1);
        acc2 = fmaf(sbs, bits_to_scaled_normal(r2), acc2);
        acc3 = fmaf(sbs, bits_to_scaled_normal(r3), acc3);
    }

    const float4 xv = reinterpret_cast<const float4*>(x)[gid];
    float4 ov;
    ov.x = xv.x + acc0;
    ov.y = xv.y + acc1;
    ov.z = xv.z + acc2;
    ov.w = xv.w + acc3;
    reinterpret_cast<float4*>(out)[gid] = ov;
}

extern "C" void kernel_launch(void* const* d_in, const int* in_sizes, int n_in,
                              void* d_out, int out_size, void* d_ws, size_t ws_size,
                              hipStream_t stream) {
    const float* x = (const float*)d_in[0];
    const float* betas = (const float*)d_in[1];
    float* out = (float*)d_out;
    const int n = in_sizes[0];       // 64*3*256*256 = 12,582,912 (divisible by 4)
    const int n4 = n / 4;

    // jax.random.key(1) -> key data (0, 1).
    // split (partitionable / foldlike): keys[s] = threefry2x32((0,1), (0, s)).
    KeyArr keys;
    for (int s = 0; s < NSTEPS; ++s) {
        uint32_t o0, o1;
        threefry2x32_host(0u, 1u, 0u, (uint32_t)s, o0, o1);
        keys.k1[s] = o0;
        keys.k2[s] = o1;
    }

    const int blocks = (n4 + 255) / 256;
    hipLaunchKernelGGL(DiffusionProcess_21698174780217_kernel,
                       dim3(blocks), dim3(256), 0, stream,
                       x, betas, out, keys, n4);
}